// Round 9
// baseline (58.326 us; speedup 1.0000x reference)
//
#include <hip/hip_runtime.h>
#include <hip/hip_bf16.h>

typedef __attribute__((ext_vector_type(8))) short bf16x8;
typedef __attribute__((ext_vector_type(4))) float f32x4;

#define B_ROWS 8192
#define FDIM 128
#define WAVE_COLS 256
#define TILE_COLS 16
#define NT 16            // tiles per wave
#define NCHUNK 32        // 8192 / 256

#define GLOAD_LDS(gp, lp) __builtin_amdgcn_global_load_lds( \
    (const __attribute__((address_space(1))) unsigned*)(gp), \
    (__attribute__((address_space(3))) unsigned*)(lp), 16, 0, 0)

#define LOG2E 1.4426950408889634f

#if __has_builtin(__builtin_amdgcn_exp2f)
__device__ __forceinline__ float fast_exp2(float x) { return __builtin_amdgcn_exp2f(x); }
#else
__device__ __forceinline__ float fast_exp2(float x) {
    float r; asm("v_exp_f32 %0, %1\n\ts_nop 0" : "=v"(r) : "v"(x)); return r;
}
#endif

// ---------------- Kernel A: normalize; z1n scaled by log2(e); pos[i] exact ----------------
__global__ __launch_bounds__(256) void simclr_norm(const float* __restrict__ z1,
                                                   const float* __restrict__ z2,
                                                   __hip_bfloat16* __restrict__ z1n,
                                                   __hip_bfloat16* __restrict__ z2n,
                                                   float* __restrict__ pos) {
    int row  = (blockIdx.x * 256 + threadIdx.x) >> 6;   // one wave per row
    int lane = threadIdx.x & 63;
    int c = lane * 2;
    const float2 v1 = *(const float2*)(z1 + row * FDIM + c);
    const float2 v2 = *(const float2*)(z2 + row * FDIM + c);
    float s1 = v1.x * v1.x + v1.y * v1.y;
    float s2 = v2.x * v2.x + v2.y * v2.y;
    for (int m = 32; m > 0; m >>= 1) { s1 += __shfl_xor(s1, m); s2 += __shfl_xor(s2, m); }
    float inv1 = 1.0f / fmaxf(sqrtf(s1), 1e-12f);
    float inv2 = 1.0f / fmaxf(sqrtf(s2), 1e-12f);
    float a0 = v1.x * inv1, a1 = v1.y * inv1;
    float b0 = v2.x * inv2, b1 = v2.y * inv2;
    // S' = (log2e * z1n) . z2n  ->  2^S' == e^S in the row-sum
    z1n[row * FDIM + c]     = __float2bfloat16(a0 * LOG2E);
    z1n[row * FDIM + c + 1] = __float2bfloat16(a1 * LOG2E);
    z2n[row * FDIM + c]     = __float2bfloat16(b0);
    z2n[row * FDIM + c + 1] = __float2bfloat16(b1);
    float p = a0 * b0 + a1 * b1;                        // unscaled positive logit
    for (int m = 32; m > 0; m >>= 1) p += __shfl_xor(p, m);
    if (lane == 0) pos[row] = p;
}

// ---------------- Kernel B: barrier-FREE wave-private 4-deep-LDS GEMM + exp2 + row-sum ----------------
// 256 threads / 4 fully independent waves; NO __syncthreads. Each wave owns
// 64 rows (A in regs, a[4][4]) x its OWN 256-col chunk, iterated as 16 tiles
// of 16 cols. B tile (16 cols x 128 K = 4 KB) staged into a wave-private
// 4x4KB LDS ring via async global_load_lds, 3 tiles ahead; the wave waits
// only with counted s_waitcnt vmcnt(12) (12 = 3 in-flight tiles x 4 loads),
// never draining to 0 mid-loop (T4). Stage->use distance ~600 cyc covers the
// L2 round-trip that stalled the 2-deep version (round 8: MfmaUtil 13.5%,
// per-tile vmcnt stall). Overwrite hazard: stage target = buffer this wave
// finished computing 1 iteration ago (wave-private, program-ordered -> safe).
__global__ __launch_bounds__(256) void simclr_gemm(const __hip_bfloat16* __restrict__ z1n,
                                                   const __hip_bfloat16* __restrict__ z2n,
                                                   float* __restrict__ rsPart) {
    __shared__ unsigned char smem[65536];   // 4 waves x 4 bufs x 4 KB, wave-private
    const int tid = threadIdx.x;
    const int wid = tid >> 6, lane = tid & 63;
    const int lq = lane >> 4, lr = lane & 15;
    const int rowBase = blockIdx.y * 64;               // block's (and each wave's) 64 rows
    const int chunk = blockIdx.x * 4 + wid;            // wave-private col chunk
    const int colBase = chunk * WAVE_COLS;
    unsigned char* myLds = smem + wid * 16384;

    const unsigned short* g1 = (const unsigned short*)z1n;
    const unsigned short* g2 = (const unsigned short*)z2n;

    // pre-swizzled per-lane global B sources (instr j covers B-rows j*4+lq;
    // (row&7) = (j&1)*4 + lq -> two bases by j parity). Slot s of row r holds
    // global slot s ^ (r&7) -> read addr uses the same XOR.
    const unsigned short* bsrc0 = g2 + (size_t)(colBase + lq) * FDIM + (lr ^ lq) * 8;
    const unsigned short* bsrc1 = g2 + (size_t)(colBase + lq) * FDIM + (lr ^ (4 + lq)) * 8;

    // stage tile t (16 B-rows x 128 K) into ring buffer byte-offset `buf`
#define STAGE(t, buf) do {                                                        \
        _Pragma("unroll")                                                         \
        for (int j = 0; j < 4; ++j) {                                             \
            const unsigned short* gp = ((j & 1) ? bsrc1 : bsrc0)                  \
                                       + (size_t)((t) * TILE_COLS + j * 4) * FDIM;\
            GLOAD_LDS(gp, myLds + (buf) + j * 1024);                              \
        }                                                                         \
    } while (0)

    // prologue: fill 3 of the 4 ring slots
    STAGE(0, 0);
    STAGE(1, 4096);
    STAGE(2, 8192);

    // A fragments -> registers (once): wave's 64 rows x 128 k (older than the
    // newest 12 VMEM ops -> any vmcnt(12) also guarantees them complete)
    bf16x8 a[4][4];
#pragma unroll
    for (int m = 0; m < 4; ++m) {
        const unsigned short* rp = g1 + (size_t)(rowBase + m * 16 + lr) * FDIM + lq * 8;
#pragma unroll
        for (int kk = 0; kk < 4; ++kk)
            a[m][kk] = *(const bf16x8*)(rp + kk * 32);
    }

    // precomputed swizzled LDS read offsets (one per kk) — zero inner-loop VALU
    int rdA[4];
#pragma unroll
    for (int kk = 0; kk < 4; ++kk)
        rdA[kk] = lr * 256 + ((kk * 64 + lq * 16) ^ ((lr & 7) << 4));

    float rowsum[4][4] = {};
    const f32x4 z4 = {0.0f, 0.0f, 0.0f, 0.0f};

    // compute one 64x16 tile from ring buffer byte-offset `buf`
#define COMPUTE(buf) do {                                                         \
        const unsigned char* bp = myLds + (buf);                                  \
        bf16x8 b0 = *(const bf16x8*)(bp + rdA[0]);                                \
        bf16x8 b1 = *(const bf16x8*)(bp + rdA[1]);                                \
        bf16x8 b2 = *(const bf16x8*)(bp + rdA[2]);                                \
        bf16x8 b3 = *(const bf16x8*)(bp + rdA[3]);                                \
        f32x4 acc[4];                                                             \
        __builtin_amdgcn_s_setprio(1);                                            \
        _Pragma("unroll")                                                         \
        for (int m = 0; m < 4; ++m)                                               \
            acc[m] = __builtin_amdgcn_mfma_f32_16x16x32_bf16(a[m][0], b0, z4, 0, 0, 0); \
        _Pragma("unroll")                                                         \
        for (int m = 0; m < 4; ++m)                                               \
            acc[m] = __builtin_amdgcn_mfma_f32_16x16x32_bf16(a[m][1], b1, acc[m], 0, 0, 0); \
        _Pragma("unroll")                                                         \
        for (int m = 0; m < 4; ++m)                                               \
            acc[m] = __builtin_amdgcn_mfma_f32_16x16x32_bf16(a[m][2], b2, acc[m], 0, 0, 0); \
        _Pragma("unroll")                                                         \
        for (int m = 0; m < 4; ++m)                                               \
            acc[m] = __builtin_amdgcn_mfma_f32_16x16x32_bf16(a[m][3], b3, acc[m], 0, 0, 0); \
        __builtin_amdgcn_s_setprio(0);                                            \
        _Pragma("unroll")                                                         \
        for (int m = 0; m < 4; ++m)                                               \
            _Pragma("unroll")                                                     \
            for (int r = 0; r < 4; ++r)                                           \
                rowsum[m][r] += fast_exp2(acc[m][r]);                             \
    } while (0)

    // main loop, fully unrolled: compile-time ring offsets + vmcnt immediates
#pragma unroll
    for (int t = 0; t < NT; ++t) {
        if (t < NT - 3) {
            STAGE(t + 3, ((t + 3) & 3) * 4096);
            asm volatile("s_waitcnt vmcnt(12)" ::: "memory");   // tile t ready; 3 in flight
        } else if (t == NT - 3) {
            asm volatile("s_waitcnt vmcnt(8)" ::: "memory");
        } else if (t == NT - 2) {
            asm volatile("s_waitcnt vmcnt(4)" ::: "memory");
        } else {
            asm volatile("s_waitcnt vmcnt(0)" ::: "memory");
        }
        COMPUTE((t & 3) * 4096);
    }
#undef STAGE
#undef COMPUTE

    // reduce across the 16 col-lanes; one plain store per row (no atomics)
#pragma unroll
    for (int m = 0; m < 4; ++m)
#pragma unroll
        for (int r = 0; r < 4; ++r) {
            float s = rowsum[m][r];
            s += __shfl_xor(s, 1); s += __shfl_xor(s, 2);
            s += __shfl_xor(s, 4); s += __shfl_xor(s, 8);
            if (lr == 0)
                rsPart[chunk * B_ROWS + rowBase + m * 16 + lq * 4 + r] = s;
        }
}

// ---------------- Kernel C: loss = mean(log(rowsum) - pos) ----------------
__global__ __launch_bounds__(256) void simclr_finish(const float* __restrict__ rsPart,
                                                     const float* __restrict__ pos,
                                                     float* __restrict__ out) {
    __shared__ float red[4];
    int i = blockIdx.x * 256 + threadIdx.x;   // one thread per row, 32 blocks
    float R = 0.0f;
#pragma unroll
    for (int c = 0; c < NCHUNK; ++c) R += rsPart[c * B_ROWS + i];
    float s = logf(R) - pos[i];
    for (int m = 32; m > 0; m >>= 1) s += __shfl_xor(s, m);
    if ((threadIdx.x & 63) == 0) red[threadIdx.x >> 6] = s;
    __syncthreads();
    if (threadIdx.x == 0) {
        float v = (red[0] + red[1]) + (red[2] + red[3]);
        atomicAdd(out, v * (1.0f / (float)B_ROWS));
    }
}

extern "C" void kernel_launch(void* const* d_in, const int* in_sizes, int n_in,
                              void* d_out, int out_size, void* d_ws, size_t ws_size,
                              hipStream_t stream) {
    const float* z1 = (const float*)d_in[0];
    const float* z2 = (const float*)d_in[1];
    float* out = (float*)d_out;
    char* ws = (char*)d_ws;

    __hip_bfloat16* z1n = (__hip_bfloat16*)ws;                       // 2 MB
    __hip_bfloat16* z2n = (__hip_bfloat16*)(ws + 2097152);           // 2 MB
    float* pos          = (float*)(ws + 4194304);                    // 32 KB
    float* rsPart       = (float*)(ws + 4194304 + 32768);            // 1 MB

    hipMemsetAsync(out, 0, sizeof(float), stream);
    simclr_norm<<<B_ROWS / 4, 256, 0, stream>>>(z1, z2, z1n, z2n, pos);
    // blockIdx.x = chunk group (8 x 4 waves = 32 chunks), blockIdx.y = row
    // group (128 x 64 rows): 1024 blocks, 64KB LDS -> 2/CU (VGPR-capped anyway).
    simclr_gemm<<<dim3(8, 128), 256, 0, stream>>>(z1n, z2n, rsPart);
    simclr_finish<<<B_ROWS / 256, 256, 0, stream>>>(rsPart, pos, out);
}

// Round 10
// 45.924 us; speedup vs baseline: 1.2701x; 1.2701x over previous
//
#include <hip/hip_runtime.h>
#include <hip/hip_bf16.h>
#include <hip/hip_fp8.h>

typedef __attribute__((ext_vector_type(8))) int i32x8;
typedef __attribute__((ext_vector_type(4))) float f32x4;

#define B_ROWS 8192
#define FDIM 128
#define WAVE_COLS 256
#define NT 16            // 16-col tiles per wave
#define NCHUNK 32        // 8192 / 256
#define LOG2E 1.4426950408889634f

#define GLOAD_LDS(gp, lp) __builtin_amdgcn_global_load_lds( \
    (const __attribute__((address_space(1))) unsigned*)(gp), \
    (__attribute__((address_space(3))) unsigned*)(lp), 16, 0, 0)

#if __has_builtin(__builtin_amdgcn_exp2f)
__device__ __forceinline__ float fast_exp2(float x) { return __builtin_amdgcn_exp2f(x); }
#else
__device__ __forceinline__ float fast_exp2(float x) {
    float r; asm("v_exp_f32 %0, %1\n\ts_nop 0" : "=v"(r) : "v"(x)); return r;
}
#endif

__device__ __forceinline__ unsigned short pk_fp8(float x0, float x1) {
#if __has_builtin(__builtin_amdgcn_cvt_pk_fp8_f32)
    return (unsigned short)(__builtin_amdgcn_cvt_pk_fp8_f32(x0, x1, 0, false) & 0xFFFF);
#else
    __hip_fp8_e4m3 q0(x0), q1(x1);
    unsigned char b0, b1;
    __builtin_memcpy(&b0, &q0, 1); __builtin_memcpy(&b1, &q1, 1);
    return (unsigned short)(b0 | (b1 << 8));
#endif
}

// ---------------- Kernel A: normalize -> fp8(e4m3); z1 scaled by log2e; pos exact ----------------
__global__ __launch_bounds__(256) void simclr_norm(const float* __restrict__ z1,
                                                   const float* __restrict__ z2,
                                                   unsigned char* __restrict__ z1q,
                                                   unsigned char* __restrict__ z2q,
                                                   float* __restrict__ pos,
                                                   float* __restrict__ out) {
    if (blockIdx.x == 0 && threadIdx.x == 0) *out = 0.0f;   // zero the atomic target
    int row  = (blockIdx.x * 256 + threadIdx.x) >> 6;       // one wave per row
    int lane = threadIdx.x & 63;
    int c = lane * 2;
    const float2 v1 = *(const float2*)(z1 + row * FDIM + c);
    const float2 v2 = *(const float2*)(z2 + row * FDIM + c);
    float s1 = v1.x * v1.x + v1.y * v1.y;
    float s2 = v2.x * v2.x + v2.y * v2.y;
    for (int m = 32; m > 0; m >>= 1) { s1 += __shfl_xor(s1, m); s2 += __shfl_xor(s2, m); }
    float inv1 = 1.0f / fmaxf(sqrtf(s1), 1e-12f);
    float inv2 = 1.0f / fmaxf(sqrtf(s2), 1e-12f);
    float a0 = v1.x * inv1, a1 = v1.y * inv1;
    float b0 = v2.x * inv2, b1 = v2.y * inv2;
    // S' = (log2e * a) . b  ->  2^S' == e^S in the row-sum
    *(unsigned short*)(z1q + (size_t)row * FDIM + c) = pk_fp8(a0 * LOG2E, a1 * LOG2E);
    *(unsigned short*)(z2q + (size_t)row * FDIM + c) = pk_fp8(b0, b1);
    float p = a0 * b0 + a1 * b1;                            // exact fp32 positive logit
    for (int m = 32; m > 0; m >>= 1) p += __shfl_xor(p, m);
    if (lane == 0) pos[row] = p;
}

// ---------------- Kernel B: barrier-free MX-fp8 GEMM (K=128 per MFMA) + exp2 + row-sum ----------------
// 256 threads / 4 independent waves; NO __syncthreads. Wave = 64 rows (A in
// regs: 4 x i32x8 = 32 VGPR) x a private 256-col chunk, 16 tiles of 16 cols.
// One mfma_scale_f32_16x16x128 (scale=1.0: e8m0 0x7F) per 16x16 output:
// NO K-chains, 4 MFMA/tile. B tile (16 cols x 128 K x 1B = 2 KB) staged into
// a wave-private 2x2KB LDS ring (global_load_lds, pre-swizzled source,
// byte ^ ((row&7)<<4)); counted s_waitcnt vmcnt(2) only.
__global__ __launch_bounds__(256) void simclr_gemm(const unsigned char* __restrict__ z1q,
                                                   const unsigned char* __restrict__ z2q,
                                                   float* __restrict__ rsPart) {
    __shared__ unsigned char smem[16384];   // 4 waves x 2 bufs x 2 KB
    const int tid = threadIdx.x;
    const int wid = tid >> 6, lane = tid & 63;
    const int lq = lane >> 4, lr = lane & 15;
    const int rowBase = blockIdx.y * 64;
    const int chunk = blockIdx.x * 4 + wid;
    const int colBase = chunk * WAVE_COLS;
    unsigned char* myLds = smem + wid * 4096;

    // staging: instr j covers tile-rows j*8+(lane>>3); lane writes LDS
    // linearly at row*128 + (lane&7)*16, so the global source supplies the
    // swizzled slot (lane&7)^(row&7).
    const int srow = lane >> 3;
    const int sslot = (lane & 7) ^ srow;
    const unsigned char* gsrc = z2q + (size_t)(colBase + srow) * FDIM + sslot * 16;

#define STAGE(t, buf) do {                                        \
        GLOAD_LDS(gsrc + (t) * 2048,        myLds + (buf));       \
        GLOAD_LDS(gsrc + (t) * 2048 + 1024, myLds + (buf) + 1024);\
    } while (0)

    STAGE(0, 0);

    // A fragments: lane holds row (lane&15), k = (lane>>4)*32 .. +32 (32 fp8 = 8 VGPR)
    i32x8 a[4];
#pragma unroll
    for (int m = 0; m < 4; ++m)
        a[m] = *(const i32x8*)(z1q + (size_t)(rowBase + m * 16 + lr) * FDIM + lq * 32);

    // swizzled LDS read offsets for the B fragment (two 16B halves)
    const int sw = lr << 4;                 // ((row&7)<<4); row=lr, lr&7 folded below
    const int rd0 = lr * 128 + (( lq * 32      ) ^ ((lr & 7) << 4));
    const int rd1 = lr * 128 + (((lq * 32) + 16) ^ ((lr & 7) << 4));
    (void)sw;

    float rowsum[4][4] = {};
    const f32x4 z4 = {0.0f, 0.0f, 0.0f, 0.0f};

#pragma unroll
    for (int t = 0; t < NT; ++t) {
        const int cur = (t & 1) * 2048;
        if (t + 1 < NT) {
            STAGE(t + 1, cur ^ 2048);
            asm volatile("s_waitcnt vmcnt(2)" ::: "memory");   // tile t ready; t+1 in flight
        } else {
            asm volatile("s_waitcnt vmcnt(0)" ::: "memory");
        }
        const unsigned char* bp = myLds + cur;
        uint4 u0 = *(const uint4*)(bp + rd0);
        uint4 u1 = *(const uint4*)(bp + rd1);
        i32x8 b;
        b[0] = (int)u0.x; b[1] = (int)u0.y; b[2] = (int)u0.z; b[3] = (int)u0.w;
        b[4] = (int)u1.x; b[5] = (int)u1.y; b[6] = (int)u1.z; b[7] = (int)u1.w;
        f32x4 acc[4];
#pragma unroll
        for (int m = 0; m < 4; ++m)
            acc[m] = __builtin_amdgcn_mfma_scale_f32_16x16x128_f8f6f4(
                         a[m], b, z4, 0, 0,                 // cbsz=fp8, blgp=fp8
                         0, 0x7F7F7F7F, 0, 0x7F7F7F7F);     // scales = 1.0 (e8m0 127)
        // rows: m*16 + lq*4 + r; cols: lr. 2^acc == e^S.
#pragma unroll
        for (int m = 0; m < 4; ++m)
#pragma unroll
            for (int r = 0; r < 4; ++r)
                rowsum[m][r] += fast_exp2(acc[m][r]);
    }
#undef STAGE

    // reduce across the 16 col-lanes; one plain store per row (no atomics)
#pragma unroll
    for (int m = 0; m < 4; ++m)
#pragma unroll
        for (int r = 0; r < 4; ++r) {
            float s = rowsum[m][r];
            s += __shfl_xor(s, 1); s += __shfl_xor(s, 2);
            s += __shfl_xor(s, 4); s += __shfl_xor(s, 8);
            if (lr == 0)
                rsPart[chunk * B_ROWS + rowBase + m * 16 + lq * 4 + r] = s;
        }
}

// ---------------- Kernel C: loss = mean(log(rowsum) - pos) ----------------
__global__ __launch_bounds__(256) void simclr_finish(const float* __restrict__ rsPart,
                                                     const float* __restrict__ pos,
                                                     float* __restrict__ out) {
    __shared__ float red[4];
    int i = blockIdx.x * 256 + threadIdx.x;   // one thread per row, 32 blocks
    float R = 0.0f;
#pragma unroll
    for (int c = 0; c < NCHUNK; ++c) R += rsPart[c * B_ROWS + i];
    float s = logf(R) - pos[i];
    for (int m = 32; m > 0; m >>= 1) s += __shfl_xor(s, m);
    if ((threadIdx.x & 63) == 0) red[threadIdx.x >> 6] = s;
    __syncthreads();
    if (threadIdx.x == 0) {
        float v = (red[0] + red[1]) + (red[2] + red[3]);
        atomicAdd(out, v * (1.0f / (float)B_ROWS));
    }
}

extern "C" void kernel_launch(void* const* d_in, const int* in_sizes, int n_in,
                              void* d_out, int out_size, void* d_ws, size_t ws_size,
                              hipStream_t stream) {
    const float* z1 = (const float*)d_in[0];
    const float* z2 = (const float*)d_in[1];
    float* out = (float*)d_out;
    char* ws = (char*)d_ws;

    unsigned char* z1q = (unsigned char*)ws;                 // 1 MB
    unsigned char* z2q = (unsigned char*)(ws + 1048576);     // 1 MB
    float* pos         = (float*)(ws + 2097152);             // 32 KB
    float* rsPart      = (float*)(ws + 2097152 + 32768);     // 1 MB

    simclr_norm<<<B_ROWS / 4, 256, 0, stream>>>(z1, z2, z1q, z2q, pos, out);
    // 1024 blocks (8 chunk-groups x 128 row-groups), 16KB LDS, target 4-5/CU
    simclr_gemm<<<dim3(8, 128), 256, 0, stream>>>(z1q, z2q, rsPart);
    simclr_finish<<<B_ROWS / 256, 256, 0, stream>>>(rsPart, pos, out);
}